// Round 1
// baseline (668.134 us; speedup 1.0000x reference)
//
#include <hip/hip_runtime.h>
#include <hip/hip_bf16.h>

#define B_ 8
#define N_ 100000
#define M_ 2048
#define K_ 32
#define D_ 128
#define KP 160   // padded GEMM1 K: 128 feat + 3 rel + 1 dist + 1 bias-one + 27 zero
#define EPS_ 1e-5f

typedef __attribute__((ext_vector_type(8))) short bf16x8;
typedef __attribute__((ext_vector_type(4))) float f32x4;

__device__ __forceinline__ short f2bf(float f) {
    unsigned int u = __builtin_bit_cast(unsigned int, f);
    u += 0x7fffu + ((u >> 16) & 1u);   // round-to-nearest-even
    return (short)(u >> 16);
}
__device__ __forceinline__ float bf2f(short s) {
    unsigned int u = ((unsigned int)(unsigned short)s) << 16;
    return __builtin_bit_cast(float, u);
}

// ---------------------------------------------------------------------------
// prep: block 0 builds W1^T bf16 [128][KP] (k=132 column holds b1, rest zero-pad);
//       blocks 1..8 compute FiLM gamma/beta = task_emb @ Wf + bf  -> gb[b][256]
// ---------------------------------------------------------------------------
__global__ __launch_bounds__(256) void prep_kernel(
    const float* __restrict__ W1, const float* __restrict__ b1,
    const float* __restrict__ task_emb, const float* __restrict__ Wf,
    const float* __restrict__ bfv,
    short* __restrict__ w1t, float* __restrict__ gb)
{
    if (blockIdx.x == 0) {
        for (int e = threadIdx.x; e < 128 * KP; e += 256) {
            const int n = e / KP;
            const int k = e - n * KP;
            float v = 0.f;
            if (k < 132) v = W1[k * 128 + n];
            else if (k == 132) v = b1[n];
            w1t[e] = f2bf(v);
        }
    } else {
        const int b = blockIdx.x - 1;
        const int col = threadIdx.x;          // 0..255 (gamma cols 0..127, beta 128..255)
        float acc = bfv[col];
        for (int i = 0; i < 128; ++i) acc += task_emb[b * 128 + i] * Wf[i * 256 + col];
        gb[b * 256 + col] = acc;
    }
}

// ---------------------------------------------------------------------------
// msg: one wave per supernode. GEMM1 [32 x KP] @ W1T via mfma 16x16x32 bf16,
// A-frags gathered straight from point_feat (no LDS), silu + masked mean
// reduced in-register, scaled partial agg written to d_out (scratch reuse).
// ---------------------------------------------------------------------------
__global__ __launch_bounds__(256) void msg_kernel(
    const float* __restrict__ point_feat,
    const float* __restrict__ point_xyz,
    const float* __restrict__ supernode_xyz,
    const int*   __restrict__ nidx,
    const int*   __restrict__ nmask,
    const short* __restrict__ w1t,
    float* __restrict__ agg_out,
    float* __restrict__ cflag)
{
    const int lane = threadIdx.x & 63;
    const int wave = threadIdx.x >> 6;
    const int sm = blockIdx.x * 4 + wave;      // global supernode id = b*M + m
    const int b  = sm >> 11;                   // / M_ (2048)
    const int c  = lane & 15;
    const int q  = lane >> 4;
    const long base_bm = (long)sm * K_;

    const int idx0 = nidx[base_bm + c];        // A-row for mtile 0 (k = c)
    const int idx1 = nidx[base_bm + 16 + c];   // A-row for mtile 1 (k = 16+c)

    const bool mv = (lane < K_) && (nmask[base_bm + lane] != 0);
    const unsigned long long bal = __ballot(mv);
    const int cnt = __popcll(bal);
    const float inv_d = 1.0f / (float)(cnt > 0 ? cnt : 1);

    const float* sxp = supernode_xyz + (long)sm * 3;
    const float sx = sxp[0], sy = sxp[1], sz = sxp[2];

    union U { bf16x8 v; short s[8]; };

    // k-step 4 A-frags (cols 128..159): quad 0 = [rel.x, rel.y, rel.z, dist, 1, 0,0,0]
    U a4[2];
    {
        const int idxs[2] = { idx0, idx1 };
        #pragma unroll
        for (int tt = 0; tt < 2; ++tt) {
            U u;
            #pragma unroll
            for (int jj = 0; jj < 8; ++jj) u.s[jj] = 0;
            if (q == 0) {
                const float* p = point_xyz + ((long)b * N_ + idxs[tt]) * 3;
                const float rx = p[0] - sx, ry = p[1] - sy, rz = p[2] - sz;
                const float dd = sqrtf(rx * rx + ry * ry + rz * rz);
                u.s[0] = f2bf(rx); u.s[1] = f2bf(ry); u.s[2] = f2bf(rz);
                u.s[3] = f2bf(dd); u.s[4] = f2bf(1.0f);
            }
            a4[tt] = u;
        }
    }

    const f32x4 zero = { 0.f, 0.f, 0.f, 0.f };
    f32x4 acc[2][8];
    #pragma unroll
    for (int mt = 0; mt < 2; ++mt)
        #pragma unroll
        for (int nt = 0; nt < 8; ++nt) acc[mt][nt] = zero;

    const float* featb = point_feat + (long)b * N_ * D_;
    const float* prow0 = featb + (long)idx0 * D_ + q * 8;
    const float* prow1 = featb + (long)idx1 * D_ + q * 8;
    const short* wbase = w1t + c * KP + q * 8;

    #pragma unroll
    for (int ks = 0; ks < 4; ++ks) {
        bf16x8 bfr[8];
        #pragma unroll
        for (int nt = 0; nt < 8; ++nt)
            bfr[nt] = *reinterpret_cast<const bf16x8*>(wbase + nt * 16 * KP + ks * 32);
        U ua0, ua1;
        {
            const f32x4 x0 = *reinterpret_cast<const f32x4*>(prow0 + ks * 32);
            const f32x4 x1 = *reinterpret_cast<const f32x4*>(prow0 + ks * 32 + 4);
            const f32x4 y0 = *reinterpret_cast<const f32x4*>(prow1 + ks * 32);
            const f32x4 y1 = *reinterpret_cast<const f32x4*>(prow1 + ks * 32 + 4);
            #pragma unroll
            for (int jj = 0; jj < 4; ++jj) {
                ua0.s[jj] = f2bf(x0[jj]); ua0.s[4 + jj] = f2bf(x1[jj]);
                ua1.s[jj] = f2bf(y0[jj]); ua1.s[4 + jj] = f2bf(y1[jj]);
            }
        }
        #pragma unroll
        for (int nt = 0; nt < 8; ++nt) {
            acc[0][nt] = __builtin_amdgcn_mfma_f32_16x16x32_bf16(ua0.v, bfr[nt], acc[0][nt], 0, 0, 0);
            acc[1][nt] = __builtin_amdgcn_mfma_f32_16x16x32_bf16(ua1.v, bfr[nt], acc[1][nt], 0, 0, 0);
        }
    }
    // k-step 4: rel/dist/bias-one columns
    #pragma unroll
    for (int nt = 0; nt < 8; ++nt) {
        const bf16x8 bfr = *reinterpret_cast<const bf16x8*>(wbase + nt * 16 * KP + 4 * 32);
        acc[0][nt] = __builtin_amdgcn_mfma_f32_16x16x32_bf16(a4[0].v, bfr, acc[0][nt], 0, 0, 0);
        acc[1][nt] = __builtin_amdgcn_mfma_f32_16x16x32_bf16(a4[1].v, bfr, acc[1][nt], 0, 0, 0);
    }

    // silu + masked sum over the 32 rows (neighbors), then scale by 1/denom.
    // C/D layout: col = lane&15, row = quad*4 + reg (+16 per mtile).
    #pragma unroll
    for (int nt = 0; nt < 8; ++nt) {
        float part = 0.f;
        #pragma unroll
        for (int mt = 0; mt < 2; ++mt) {
            #pragma unroll
            for (int r = 0; r < 4; ++r) {
                const int row = mt * 16 + q * 4 + r;
                const float v = acc[mt][nt][r];
                const float s = v / (1.0f + __expf(-v));   // silu
                part += ((bal >> row) & 1ULL) ? s : 0.0f;
            }
        }
        part += __shfl_xor(part, 16);
        part += __shfl_xor(part, 32);
        if (q == 0) agg_out[(long)sm * D_ + nt * 16 + c] = part * inv_d;
    }
    if (lane == 0) cflag[sm] = (cnt > 0) ? 1.0f : 0.0f;
}

// ---------------------------------------------------------------------------
// out: agg@W2 + cnt_flag*b2, FiLM, residual, LayerNorm. In-place on d_out.
// ---------------------------------------------------------------------------
__global__ __launch_bounds__(256) void out_kernel(
    float* __restrict__ inout,
    const float* __restrict__ W2,
    const float* __restrict__ b2,
    const float* __restrict__ cflag,
    const float* __restrict__ gb,
    const float* __restrict__ init_feat,
    const float* __restrict__ ln_g,
    const float* __restrict__ ln_b)
{
    __shared__ short sW2[128 * 128];   // 32 KB, bf16
    __shared__ float sA[128];
    __shared__ float sPart[256];
    __shared__ float sRed[8];

    const int t = threadIdx.x;
    for (int i = t; i < 128 * 128; i += 256) sW2[i] = f2bf(W2[i]);

    const int j = t & 127;
    const int p = t >> 7;
    const int s0 = blockIdx.x * 16;
    __syncthreads();

    for (int si = 0; si < 16; ++si) {
        const int s = s0 + si;
        if (t < 128) sA[t] = inout[(long)s * D_ + t];
        __syncthreads();
        float partial = 0.f;
        #pragma unroll 8
        for (int i = p * 64; i < p * 64 + 64; ++i)
            partial += sA[i] * bf2f(sW2[i * 128 + j]);
        sPart[t] = partial;
        __syncthreads();
        const int b = s >> 11;
        float h = 0.f;
        if (t < 128) {
            const float msg = sPart[j] + sPart[128 + j] + cflag[s] * b2[j];
            const float g  = gb[b * 256 + j];
            const float be = gb[b * 256 + 128 + j];
            const float v = msg * (1.f + g) + be;
            h = init_feat[(long)s * D_ + j] + v;
        }
        float a1 = h, a2 = h * h;
        #pragma unroll
        for (int off = 32; off > 0; off >>= 1) {
            a1 += __shfl_xor(a1, off);
            a2 += __shfl_xor(a2, off);
        }
        if ((t & 63) == 0) { sRed[t >> 6] = a1; sRed[4 + (t >> 6)] = a2; }
        __syncthreads();
        const float mu  = (sRed[0] + sRed[1]) * (1.f / 128.f);
        const float var = (sRed[4] + sRed[5]) * (1.f / 128.f) - mu * mu;
        if (t < 128) {
            const float o = (h - mu) * rsqrtf(var + EPS_) * ln_g[j] + ln_b[j];
            inout[(long)s * D_ + j] = o;
        }
        __syncthreads();
    }
}

extern "C" void kernel_launch(void* const* d_in, const int* in_sizes, int n_in,
                              void* d_out, int out_size, void* d_ws, size_t ws_size,
                              hipStream_t stream) {
    const float* point_feat     = (const float*)d_in[0];
    const float* point_xyz      = (const float*)d_in[1];
    const float* supernode_xyz  = (const float*)d_in[2];
    const int*   neighbor_idx   = (const int*)d_in[3];
    const int*   neighbor_mask  = (const int*)d_in[4];
    const float* supernode_init = (const float*)d_in[5];
    const float* task_emb       = (const float*)d_in[6];
    const float* W1             = (const float*)d_in[7];
    const float* b1             = (const float*)d_in[8];
    const float* W2             = (const float*)d_in[9];
    const float* b2             = (const float*)d_in[10];
    const float* Wf             = (const float*)d_in[11];
    const float* bfv            = (const float*)d_in[12];
    const float* ln_g           = (const float*)d_in[13];
    const float* ln_b           = (const float*)d_in[14];

    char* ws = (char*)d_ws;
    short* w1t  = (short*)ws;                 // 128*160*2 = 40960 B
    float* gb   = (float*)(ws + 40960);       // 8*256*4   =  8192 B
    float* cfl  = (float*)(ws + 49152);       // 16384*4   = 65536 B
    float* out  = (float*)d_out;              // also used as agg scratch between kernels

    prep_kernel<<<9, 256, 0, stream>>>(W1, b1, task_emb, Wf, bfv, w1t, gb);
    msg_kernel<<<(B_ * M_) / 4, 256, 0, stream>>>(point_feat, point_xyz, supernode_xyz,
                                                  neighbor_idx, neighbor_mask, w1t, out, cfl);
    out_kernel<<<(B_ * M_) / 16, 256, 0, stream>>>(out, W2, b2, cfl, gb,
                                                   supernode_init, ln_g, ln_b);
}

// Round 2
// 590.706 us; speedup vs baseline: 1.1311x; 1.1311x over previous
//
#include <hip/hip_runtime.h>
#include <hip/hip_bf16.h>

#define B_ 8
#define N_ 100000
#define M_ 2048
#define K_ 32
#define D_ 128
#define KPL 168   // W1^T padded k-stride (shorts): 132 real + bias col + pad; 168%8==0, 2-way LDS banks
#define KL2 136   // W2^T padded k-stride
#define EPS_ 1e-5f

typedef __attribute__((ext_vector_type(8))) short bf16x8;
typedef __attribute__((ext_vector_type(4))) float f32x4;

__device__ __forceinline__ short f2bf(float f) {
    unsigned int u = __builtin_bit_cast(unsigned int, f);
    u += 0x7fffu + ((u >> 16) & 1u);   // round-to-nearest-even
    return (short)(u >> 16);
}

// ---------------------------------------------------------------------------
// prep: b0 -> W1^T bf16 [128][KPL] (k=132 col = b1, rest 0)
//       b1 -> W2^T bf16 [128][KL2]
//       b2..9 -> FiLM gamma/beta = task_emb @ Wf + bf  -> gb[b][256]
// ---------------------------------------------------------------------------
__global__ __launch_bounds__(256) void prep_kernel(
    const float* __restrict__ W1, const float* __restrict__ b1,
    const float* __restrict__ W2,
    const float* __restrict__ task_emb, const float* __restrict__ Wf,
    const float* __restrict__ bfv,
    short* __restrict__ w1t, short* __restrict__ w2t, float* __restrict__ gb)
{
    if (blockIdx.x == 0) {
        for (int e = threadIdx.x; e < 128 * KPL; e += 256) {
            const int n = e / KPL;
            const int k = e - n * KPL;
            float v = 0.f;
            if (k < 132) v = W1[k * 128 + n];
            else if (k == 132) v = b1[n];
            w1t[e] = f2bf(v);
        }
    } else if (blockIdx.x == 1) {
        for (int e = threadIdx.x; e < 128 * KL2; e += 256) {
            const int n = e / KL2;
            const int k = e - n * KL2;
            w2t[e] = f2bf(k < 128 ? W2[k * 128 + n] : 0.f);
        }
    } else {
        const int b = blockIdx.x - 2;
        const int col = threadIdx.x;          // gamma 0..127, beta 128..255
        float acc = bfv[col];
        for (int i = 0; i < 128; ++i) acc += task_emb[b * 128 + i] * Wf[i * 256 + col];
        gb[b * 256 + col] = acc;
    }
}

// ---------------------------------------------------------------------------
// msg: one wave per supernode. GEMM1 [32 x k] @ W1^T via mfma 16x16x32 bf16.
// W1^T staged in LDS; gathers predicated on neighbor mask (invalid rows are
// never fetched; their garbage accs are discarded at the ballot-select).
// ---------------------------------------------------------------------------
__global__ __launch_bounds__(256) void msg_kernel(
    const float* __restrict__ point_feat,
    const float* __restrict__ point_xyz,
    const float* __restrict__ supernode_xyz,
    const int*   __restrict__ nidx,
    const int*   __restrict__ nmask,
    const short* __restrict__ w1t,
    float* __restrict__ agg_out,
    float* __restrict__ cflag)
{
    __shared__ short sw[128 * KPL];                 // 43008 B
    {
        const uint2* src = (const uint2*)w1t;       // 5376 uint2
        uint2* dst = (uint2*)sw;
        #pragma unroll
        for (int i = 0; i < 21; ++i) dst[threadIdx.x + i * 256] = src[threadIdx.x + i * 256];
    }
    __syncthreads();

    const int lane = threadIdx.x & 63;
    const int wave = threadIdx.x >> 6;
    const int sm = blockIdx.x * 4 + wave;      // supernode id = b*M + m
    const int b  = sm >> 11;
    const int c  = lane & 15;
    const int q  = lane >> 4;
    const long base_bm = (long)sm * K_;

    const int idx0 = nidx[base_bm + c];
    const int idx1 = nidx[base_bm + 16 + c];

    const bool mv = (lane < K_) && (nmask[base_bm + lane] != 0);
    const unsigned long long bal = __ballot(mv);
    const int cnt = __popcll(bal);
    const float inv_d = 1.0f / (float)(cnt > 0 ? cnt : 1);
    const bool v0 = (bal >> c) & 1ULL;
    const bool v1 = (bal >> (16 + c)) & 1ULL;

    const float* sxp = supernode_xyz + (long)sm * 3;
    const float sx = sxp[0], sy = sxp[1], sz = sxp[2];

    union U { bf16x8 v; short s[8]; };

    // k-step 4 A-frags (cols 128..159): quad 0 = [rel.x, rel.y, rel.z, dist, 1, 0...]
    U a4[2];
    {
        const int idxs[2] = { idx0, idx1 };
        const bool vs[2] = { v0, v1 };
        #pragma unroll
        for (int tt = 0; tt < 2; ++tt) {
            U u;
            #pragma unroll
            for (int jj = 0; jj < 8; ++jj) u.s[jj] = 0;
            if (q == 0 && vs[tt]) {
                const float* p = point_xyz + ((long)b * N_ + idxs[tt]) * 3;
                const float rx = p[0] - sx, ry = p[1] - sy, rz = p[2] - sz;
                const float dd = sqrtf(rx * rx + ry * ry + rz * rz);
                u.s[0] = f2bf(rx); u.s[1] = f2bf(ry); u.s[2] = f2bf(rz);
                u.s[3] = f2bf(dd); u.s[4] = f2bf(1.0f);
            }
            a4[tt] = u;
        }
    }

    const f32x4 zero = { 0.f, 0.f, 0.f, 0.f };
    f32x4 acc[2][8];
    #pragma unroll
    for (int mt = 0; mt < 2; ++mt)
        #pragma unroll
        for (int nt = 0; nt < 8; ++nt) acc[mt][nt] = zero;

    const float* featb = point_feat + (long)b * N_ * D_;
    const float* prow0 = featb + (long)idx0 * D_ + q * 8;
    const float* prow1 = featb + (long)idx1 * D_ + q * 8;
    const short* wb = sw + c * KPL + q * 8;

    #pragma unroll
    for (int ks = 0; ks < 4; ++ks) {
        bf16x8 bfr[8];
        #pragma unroll
        for (int nt = 0; nt < 8; ++nt)
            bfr[nt] = *reinterpret_cast<const bf16x8*>(wb + nt * 16 * KPL + ks * 32);
        U ua0 = {}, ua1 = {};
        if (v0) {
            const f32x4 x0 = *reinterpret_cast<const f32x4*>(prow0 + ks * 32);
            const f32x4 x1 = *reinterpret_cast<const f32x4*>(prow0 + ks * 32 + 4);
            #pragma unroll
            for (int jj = 0; jj < 4; ++jj) { ua0.s[jj] = f2bf(x0[jj]); ua0.s[4 + jj] = f2bf(x1[jj]); }
        }
        if (v1) {
            const f32x4 y0 = *reinterpret_cast<const f32x4*>(prow1 + ks * 32);
            const f32x4 y1 = *reinterpret_cast<const f32x4*>(prow1 + ks * 32 + 4);
            #pragma unroll
            for (int jj = 0; jj < 4; ++jj) { ua1.s[jj] = f2bf(y0[jj]); ua1.s[4 + jj] = f2bf(y1[jj]); }
        }
        #pragma unroll
        for (int nt = 0; nt < 8; ++nt) {
            acc[0][nt] = __builtin_amdgcn_mfma_f32_16x16x32_bf16(ua0.v, bfr[nt], acc[0][nt], 0, 0, 0);
            acc[1][nt] = __builtin_amdgcn_mfma_f32_16x16x32_bf16(ua1.v, bfr[nt], acc[1][nt], 0, 0, 0);
        }
    }
    #pragma unroll
    for (int nt = 0; nt < 8; ++nt) {
        const bf16x8 bfr = *reinterpret_cast<const bf16x8*>(wb + nt * 16 * KPL + 4 * 32);
        acc[0][nt] = __builtin_amdgcn_mfma_f32_16x16x32_bf16(a4[0].v, bfr, acc[0][nt], 0, 0, 0);
        acc[1][nt] = __builtin_amdgcn_mfma_f32_16x16x32_bf16(a4[1].v, bfr, acc[1][nt], 0, 0, 0);
    }

    // silu + masked mean. C/D: col = lane&15, row = quad*4 + reg (+16 per mtile)
    #pragma unroll
    for (int nt = 0; nt < 8; ++nt) {
        float part = 0.f;
        #pragma unroll
        for (int mt = 0; mt < 2; ++mt) {
            #pragma unroll
            for (int r = 0; r < 4; ++r) {
                const int row = mt * 16 + q * 4 + r;
                const float v = acc[mt][nt][r];
                const float s = v / (1.0f + __expf(-v));
                part += ((bal >> row) & 1ULL) ? s : 0.0f;
            }
        }
        part += __shfl_xor(part, 16);
        part += __shfl_xor(part, 32);
        if (q == 0) agg_out[(long)sm * D_ + nt * 16 + c] = part * inv_d;
    }
    if (lane == 0) cflag[sm] = (cnt > 0) ? 1.0f : 0.0f;
}

// ---------------------------------------------------------------------------
// out: [16384 x 128] @ W2 via MFMA (+ cflag*b2, FiLM, residual, LayerNorm).
// One wave per 16 rows, W2^T staged in LDS. In-place on d_out.
// ---------------------------------------------------------------------------
__global__ __launch_bounds__(256) void out_kernel(
    float* __restrict__ inout,
    const short* __restrict__ w2t,
    const float* __restrict__ b2,
    const float* __restrict__ cflag,
    const float* __restrict__ gb,
    const float* __restrict__ init_feat,
    const float* __restrict__ ln_g,
    const float* __restrict__ ln_b)
{
    __shared__ short sw[128 * KL2];                // 34816 B
    {
        const uint2* src = (const uint2*)w2t;      // 4352 uint2
        uint2* dst = (uint2*)sw;
        #pragma unroll
        for (int i = 0; i < 17; ++i) dst[threadIdx.x + i * 256] = src[threadIdx.x + i * 256];
    }
    __syncthreads();

    const int lane = threadIdx.x & 63;
    const int wave = threadIdx.x >> 6;
    const int s0 = blockIdx.x * 64 + wave * 16;    // 16 rows per wave
    const int b  = s0 >> 11;
    const int c  = lane & 15;
    const int q  = lane >> 4;

    union U { bf16x8 v; short s[8]; };
    const f32x4 zero = { 0.f, 0.f, 0.f, 0.f };
    f32x4 acc[8];
    #pragma unroll
    for (int nt = 0; nt < 8; ++nt) acc[nt] = zero;

    const float* arow = inout + (long)(s0 + c) * D_ + q * 8;
    const short* wb = sw + c * KL2 + q * 8;

    #pragma unroll
    for (int ks = 0; ks < 4; ++ks) {
        U ua;
        {
            const f32x4 x0 = *reinterpret_cast<const f32x4*>(arow + ks * 32);
            const f32x4 x1 = *reinterpret_cast<const f32x4*>(arow + ks * 32 + 4);
            #pragma unroll
            for (int jj = 0; jj < 4; ++jj) { ua.s[jj] = f2bf(x0[jj]); ua.s[4 + jj] = f2bf(x1[jj]); }
        }
        #pragma unroll
        for (int nt = 0; nt < 8; ++nt) {
            const bf16x8 bfr = *reinterpret_cast<const bf16x8*>(wb + nt * 16 * KL2 + ks * 32);
            acc[nt] = __builtin_amdgcn_mfma_f32_16x16x32_bf16(ua.v, bfr, acc[nt], 0, 0, 0);
        }
    }

    // epilogue: col = nt*16+c, row = s0 + q*4 + r
    float gv[8], bev[8], b2v[8], lgv[8], lbv[8];
    #pragma unroll
    for (int nt = 0; nt < 8; ++nt) {
        const int col = nt * 16 + c;
        gv[nt]  = gb[b * 256 + col];
        bev[nt] = gb[b * 256 + 128 + col];
        b2v[nt] = b2[col];
        lgv[nt] = ln_g[col];
        lbv[nt] = ln_b[col];
    }

    #pragma unroll
    for (int r = 0; r < 4; ++r) {
        const int row = s0 + q * 4 + r;
        const float cf = cflag[row];
        float h[8];
        float s1 = 0.f, s2 = 0.f;
        #pragma unroll
        for (int nt = 0; nt < 8; ++nt) {
            const float msgv = acc[nt][r] + cf * b2v[nt];
            const float v = msgv * (1.f + gv[nt]) + bev[nt];
            const float hh = init_feat[(long)row * D_ + nt * 16 + c] + v;
            h[nt] = hh; s1 += hh; s2 += hh * hh;
        }
        #pragma unroll
        for (int off = 1; off < 16; off <<= 1) {
            s1 += __shfl_xor(s1, off);
            s2 += __shfl_xor(s2, off);
        }
        const float mu = s1 * (1.f / 128.f);
        const float var = s2 * (1.f / 128.f) - mu * mu;
        const float rs = rsqrtf(var + EPS_);
        #pragma unroll
        for (int nt = 0; nt < 8; ++nt)
            inout[(long)row * D_ + nt * 16 + c] = (h[nt] - mu) * rs * lgv[nt] + lbv[nt];
    }
}

extern "C" void kernel_launch(void* const* d_in, const int* in_sizes, int n_in,
                              void* d_out, int out_size, void* d_ws, size_t ws_size,
                              hipStream_t stream) {
    const float* point_feat     = (const float*)d_in[0];
    const float* point_xyz      = (const float*)d_in[1];
    const float* supernode_xyz  = (const float*)d_in[2];
    const int*   neighbor_idx   = (const int*)d_in[3];
    const int*   neighbor_mask  = (const int*)d_in[4];
    const float* supernode_init = (const float*)d_in[5];
    const float* task_emb       = (const float*)d_in[6];
    const float* W1             = (const float*)d_in[7];
    const float* b1             = (const float*)d_in[8];
    const float* W2             = (const float*)d_in[9];
    const float* b2             = (const float*)d_in[10];
    const float* Wf             = (const float*)d_in[11];
    const float* bfv            = (const float*)d_in[12];
    const float* ln_g           = (const float*)d_in[13];
    const float* ln_b           = (const float*)d_in[14];

    char* ws = (char*)d_ws;
    short* w1t  = (short*)ws;                   // 128*168*2 = 43008 B
    short* w2t  = (short*)(ws + 44032);         // 128*136*2 = 34816 B
    float* gb   = (float*)(ws + 78848);         // 8*256*4   =  8192 B
    float* cfl  = (float*)(ws + 87040);         // 16384*4   = 65536 B
    float* out  = (float*)d_out;                // agg scratch between kernels

    prep_kernel<<<10, 256, 0, stream>>>(W1, b1, W2, task_emb, Wf, bfv, w1t, w2t, gb);
    msg_kernel<<<(B_ * M_) / 4, 256, 0, stream>>>(point_feat, point_xyz, supernode_xyz,
                                                  neighbor_idx, neighbor_mask, w1t, out, cfl);
    out_kernel<<<(B_ * M_) / 64, 256, 0, stream>>>(out, w2t, b2, cfl, gb,
                                                   supernode_init, ln_g, ln_b);
}

// Round 3
// 570.920 us; speedup vs baseline: 1.1703x; 1.0347x over previous
//
#include <hip/hip_runtime.h>
#include <hip/hip_bf16.h>

#define B_ 8
#define N_ 100000
#define M_ 2048
#define K_ 32
#define D_ 128
#define KPL 168   // W1^T padded k-stride (shorts): 132 real + bias col + pad
#define KL2 136   // W2^T padded k-stride
#define EPS_ 1e-5f

typedef __attribute__((ext_vector_type(8))) short bf16x8;
typedef __attribute__((ext_vector_type(4))) float f32x4;

__device__ __forceinline__ short f2bf(float f) {
    unsigned int u = __builtin_bit_cast(unsigned int, f);
    u += 0x7fffu + ((u >> 16) & 1u);   // RNE (used only for small prep/a4 data)
    return (short)(u >> 16);
}
// pack two f32 -> two bf16 (truncation) in one v_perm_b32
__device__ __forceinline__ unsigned int pack_bf2(float lo, float hi) {
    return __builtin_amdgcn_perm(__builtin_bit_cast(unsigned int, hi),
                                 __builtin_bit_cast(unsigned int, lo),
                                 0x07060302u);
}

// ---------------------------------------------------------------------------
// prep (40 blocks): 0..15 -> W1^T bf16 [128][KPL] (k=132 col = b1, rest 0)
//                   16..31 -> W2^T bf16 [128][KL2]
//                   32..39 -> FiLM gamma/beta = task_emb @ Wf + bf -> gb[b][256]
// transposes read coalesced (n fast), write scattered (fire-and-forget).
// ---------------------------------------------------------------------------
__global__ __launch_bounds__(256) void prep_kernel(
    const float* __restrict__ W1, const float* __restrict__ b1,
    const float* __restrict__ W2,
    const float* __restrict__ task_emb, const float* __restrict__ Wf,
    const float* __restrict__ bfv,
    short* __restrict__ w1t, short* __restrict__ w2t, float* __restrict__ gb)
{
    const int t = threadIdx.x;
    if (blockIdx.x < 16) {
        const int bid = blockIdx.x;
        #pragma unroll
        for (int it = 0; it < 6; ++it) {
            const int e = bid * 1344 + it * 256 + t;    // e = k*128 + n
            if (e < (bid + 1) * 1344 && e < KPL * 128) {
                const int k = e >> 7, n = e & 127;
                float v = 0.f;
                if (k < 132) v = W1[k * 128 + n];
                else if (k == 132) v = b1[n];
                w1t[n * KPL + k] = f2bf(v);
            }
        }
    } else if (blockIdx.x < 32) {
        const int bid = blockIdx.x - 16;
        #pragma unroll
        for (int it = 0; it < 5; ++it) {
            const int e = bid * 1088 + it * 256 + t;    // e = k*128 + n
            if (e < (bid + 1) * 1088 && e < KL2 * 128) {
                const int k = e >> 7, n = e & 127;
                w2t[n * KL2 + k] = f2bf(k < 128 ? W2[k * 128 + n] : 0.f);
            }
        }
    } else {
        const int b = blockIdx.x - 32;
        float acc = bfv[t];
        for (int i = 0; i < 128; ++i) acc += task_emb[b * 128 + i] * Wf[i * 256 + t];
        gb[b * 256 + t] = acc;
    }
}

// ---------------------------------------------------------------------------
// msg: one wave per supernode. GEMM1 [32 x k] @ W1^T via mfma 16x16x32 bf16.
// Branchless gather: masked lanes read batch row 0 (cache-hot), all 16 loads
// per lane issue up-front; garbage rows discarded at the ballot-select reduce.
// ---------------------------------------------------------------------------
__global__ __launch_bounds__(256) void msg_kernel(
    const float* __restrict__ point_feat,
    const float* __restrict__ point_xyz,
    const float* __restrict__ supernode_xyz,
    const int*   __restrict__ nidx,
    const int*   __restrict__ nmask,
    const short* __restrict__ w1t,
    float* __restrict__ agg_out,
    float* __restrict__ cflag)
{
    __shared__ short sw[128 * KPL];                 // 43008 B

    const int lane = threadIdx.x & 63;
    const int wave = threadIdx.x >> 6;
    const int sm = blockIdx.x * 4 + wave;           // supernode id = b*M + m
    const int b  = sm >> 11;
    const int c  = lane & 15;
    const int q  = lane >> 4;
    const long base_bm = (long)sm * K_;

    // --- indices + mask first (longest dependency chain) ---
    const int idx0 = nidx[base_bm + c];
    const int idx1 = nidx[base_bm + 16 + c];
    const bool mv = (lane < K_) && (nmask[base_bm + lane] != 0);
    const unsigned long long bal = __ballot(mv);
    const int cnt = __popcll(bal);
    const float inv_d = 1.0f / (float)(cnt > 0 ? cnt : 1);
    const bool v0 = (bal >> c) & 1ULL;
    const bool v1 = (bal >> (16 + c)) & 1ULL;
    const int ridx0 = v0 ? idx0 : 0;               // clamp masked lanes to hot row 0
    const int ridx1 = v1 ? idx1 : 0;

    // --- issue ALL gather loads (unconditional, fully pipelined) ---
    const float* featb = point_feat + (long)b * N_ * D_;
    const float* prow0 = featb + (long)ridx0 * D_ + q * 8;
    const float* prow1 = featb + (long)ridx1 * D_ + q * 8;
    f32x4 r0[8], r1[8];
    #pragma unroll
    for (int ks = 0; ks < 4; ++ks) {
        r0[2 * ks]     = *reinterpret_cast<const f32x4*>(prow0 + ks * 32);
        r0[2 * ks + 1] = *reinterpret_cast<const f32x4*>(prow0 + ks * 32 + 4);
        r1[2 * ks]     = *reinterpret_cast<const f32x4*>(prow1 + ks * 32);
        r1[2 * ks + 1] = *reinterpret_cast<const f32x4*>(prow1 + ks * 32 + 4);
    }

    // --- xyz (clamped rows, all lanes; only q==0 values used) ---
    const float* sxp = supernode_xyz + (long)sm * 3;
    const float sx = sxp[0], sy = sxp[1], sz = sxp[2];
    const float* p0 = point_xyz + ((long)b * N_ + ridx0) * 3;
    const float* p1 = point_xyz + ((long)b * N_ + ridx1) * 3;
    const float rx0 = p0[0] - sx, ry0 = p0[1] - sy, rz0 = p0[2] - sz;
    const float rx1 = p1[0] - sx, ry1 = p1[1] - sy, rz1 = p1[2] - sz;
    const float dd0 = sqrtf(rx0 * rx0 + ry0 * ry0 + rz0 * rz0);
    const float dd1 = sqrtf(rx1 * rx1 + ry1 * ry1 + rz1 * rz1);

    union U { bf16x8 v; short s[8]; unsigned int u[4]; };
    U a4[2];
    #pragma unroll
    for (int jj = 0; jj < 8; ++jj) { a4[0].s[jj] = 0; a4[1].s[jj] = 0; }
    if (q == 0) {
        a4[0].s[0] = f2bf(rx0); a4[0].s[1] = f2bf(ry0); a4[0].s[2] = f2bf(rz0);
        a4[0].s[3] = f2bf(dd0); a4[0].s[4] = f2bf(1.0f);
        a4[1].s[0] = f2bf(rx1); a4[1].s[1] = f2bf(ry1); a4[1].s[2] = f2bf(rz1);
        a4[1].s[3] = f2bf(dd1); a4[1].s[4] = f2bf(1.0f);
    }

    // --- stage W1^T into LDS (L2-hot; latency hidden under the gathers) ---
    {
        const uint2* src = (const uint2*)w1t;       // 5376 uint2
        uint2* dst = (uint2*)sw;
        #pragma unroll
        for (int i = 0; i < 21; ++i) dst[threadIdx.x + i * 256] = src[threadIdx.x + i * 256];
    }
    __syncthreads();

    // --- convert gathered rows to bf16 A-frags (v_perm truncation) ---
    U a0[4], a1[4];
    #pragma unroll
    for (int ks = 0; ks < 4; ++ks) {
        const f32x4 x0 = r0[2 * ks], x1 = r0[2 * ks + 1];
        const f32x4 y0 = r1[2 * ks], y1 = r1[2 * ks + 1];
        a0[ks].u[0] = pack_bf2(x0[0], x0[1]);
        a0[ks].u[1] = pack_bf2(x0[2], x0[3]);
        a0[ks].u[2] = pack_bf2(x1[0], x1[1]);
        a0[ks].u[3] = pack_bf2(x1[2], x1[3]);
        a1[ks].u[0] = pack_bf2(y0[0], y0[1]);
        a1[ks].u[1] = pack_bf2(y0[2], y0[3]);
        a1[ks].u[2] = pack_bf2(y1[0], y1[1]);
        a1[ks].u[3] = pack_bf2(y1[2], y1[3]);
    }

    const f32x4 zero = { 0.f, 0.f, 0.f, 0.f };
    f32x4 acc[2][8];
    #pragma unroll
    for (int mt = 0; mt < 2; ++mt)
        #pragma unroll
        for (int nt = 0; nt < 8; ++nt) acc[mt][nt] = zero;

    const short* wb = sw + c * KPL + q * 8;
    #pragma unroll
    for (int ks = 0; ks < 4; ++ks) {
        #pragma unroll
        for (int nt = 0; nt < 8; ++nt) {
            const bf16x8 bfr = *reinterpret_cast<const bf16x8*>(wb + nt * 16 * KPL + ks * 32);
            acc[0][nt] = __builtin_amdgcn_mfma_f32_16x16x32_bf16(a0[ks].v, bfr, acc[0][nt], 0, 0, 0);
            acc[1][nt] = __builtin_amdgcn_mfma_f32_16x16x32_bf16(a1[ks].v, bfr, acc[1][nt], 0, 0, 0);
        }
    }
    #pragma unroll
    for (int nt = 0; nt < 8; ++nt) {
        const bf16x8 bfr = *reinterpret_cast<const bf16x8*>(wb + nt * 16 * KPL + 4 * 32);
        acc[0][nt] = __builtin_amdgcn_mfma_f32_16x16x32_bf16(a4[0].v, bfr, acc[0][nt], 0, 0, 0);
        acc[1][nt] = __builtin_amdgcn_mfma_f32_16x16x32_bf16(a4[1].v, bfr, acc[1][nt], 0, 0, 0);
    }

    // silu + masked mean. C/D: col = lane&15, row = quad*4 + reg (+16 per mtile)
    #pragma unroll
    for (int nt = 0; nt < 8; ++nt) {
        float part = 0.f;
        #pragma unroll
        for (int mt = 0; mt < 2; ++mt) {
            #pragma unroll
            for (int r = 0; r < 4; ++r) {
                const int row = mt * 16 + q * 4 + r;
                const float v = acc[mt][nt][r];
                const float s = v / (1.0f + __expf(-v));
                part += ((bal >> row) & 1ULL) ? s : 0.0f;
            }
        }
        part += __shfl_xor(part, 16);
        part += __shfl_xor(part, 32);
        if (q == 0) agg_out[(long)sm * D_ + nt * 16 + c] = part * inv_d;
    }
    if (lane == 0) cflag[sm] = (cnt > 0) ? 1.0f : 0.0f;
}

// ---------------------------------------------------------------------------
// out: [16384 x 128] @ W2 via MFMA (+ cflag*b2, FiLM, residual, LayerNorm).
// One wave per 16 rows, W2^T staged in LDS. In-place on d_out.
// ---------------------------------------------------------------------------
__global__ __launch_bounds__(256) void out_kernel(
    float* __restrict__ inout,
    const short* __restrict__ w2t,
    const float* __restrict__ b2,
    const float* __restrict__ cflag,
    const float* __restrict__ gb,
    const float* __restrict__ init_feat,
    const float* __restrict__ ln_g,
    const float* __restrict__ ln_b)
{
    __shared__ short sw[128 * KL2];                // 34816 B
    {
        const uint2* src = (const uint2*)w2t;      // 4352 uint2
        uint2* dst = (uint2*)sw;
        #pragma unroll
        for (int i = 0; i < 17; ++i) dst[threadIdx.x + i * 256] = src[threadIdx.x + i * 256];
    }
    __syncthreads();

    const int lane = threadIdx.x & 63;
    const int wave = threadIdx.x >> 6;
    const int s0 = blockIdx.x * 64 + wave * 16;    // 16 rows per wave
    const int b  = s0 >> 11;
    const int c  = lane & 15;
    const int q  = lane >> 4;

    union U { bf16x8 v; short s[8]; unsigned int u[4]; };
    const f32x4 zero = { 0.f, 0.f, 0.f, 0.f };
    f32x4 acc[8];
    #pragma unroll
    for (int nt = 0; nt < 8; ++nt) acc[nt] = zero;

    const float* arow = inout + (long)(s0 + c) * D_ + q * 8;
    const short* wb = sw + c * KL2 + q * 8;

    #pragma unroll
    for (int ks = 0; ks < 4; ++ks) {
        U ua;
        {
            const f32x4 x0 = *reinterpret_cast<const f32x4*>(arow + ks * 32);
            const f32x4 x1 = *reinterpret_cast<const f32x4*>(arow + ks * 32 + 4);
            ua.u[0] = pack_bf2(x0[0], x0[1]);
            ua.u[1] = pack_bf2(x0[2], x0[3]);
            ua.u[2] = pack_bf2(x1[0], x1[1]);
            ua.u[3] = pack_bf2(x1[2], x1[3]);
        }
        #pragma unroll
        for (int nt = 0; nt < 8; ++nt) {
            const bf16x8 bfr = *reinterpret_cast<const bf16x8*>(wb + nt * 16 * KL2 + ks * 32);
            acc[nt] = __builtin_amdgcn_mfma_f32_16x16x32_bf16(ua.v, bfr, acc[nt], 0, 0, 0);
        }
    }

    // epilogue: col = nt*16+c, row = s0 + q*4 + r
    float gv[8], bev[8], b2v[8], lgv[8], lbv[8];
    #pragma unroll
    for (int nt = 0; nt < 8; ++nt) {
        const int col = nt * 16 + c;
        gv[nt]  = gb[b * 256 + col];
        bev[nt] = gb[b * 256 + 128 + col];
        b2v[nt] = b2[col];
        lgv[nt] = ln_g[col];
        lbv[nt] = ln_b[col];
    }

    #pragma unroll
    for (int r = 0; r < 4; ++r) {
        const int row = s0 + q * 4 + r;
        const float cf = cflag[row];
        float h[8];
        float s1 = 0.f, s2 = 0.f;
        #pragma unroll
        for (int nt = 0; nt < 8; ++nt) {
            const float msgv = acc[nt][r] + cf * b2v[nt];
            const float v = msgv * (1.f + gv[nt]) + bev[nt];
            const float hh = init_feat[(long)row * D_ + nt * 16 + c] + v;
            h[nt] = hh; s1 += hh; s2 += hh * hh;
        }
        #pragma unroll
        for (int off = 1; off < 16; off <<= 1) {
            s1 += __shfl_xor(s1, off);
            s2 += __shfl_xor(s2, off);
        }
        const float mu = s1 * (1.f / 128.f);
        const float var = s2 * (1.f / 128.f) - mu * mu;
        const float rs = rsqrtf(var + EPS_);
        #pragma unroll
        for (int nt = 0; nt < 8; ++nt)
            inout[(long)row * D_ + nt * 16 + c] = (h[nt] - mu) * rs * lgv[nt] + lbv[nt];
    }
}

extern "C" void kernel_launch(void* const* d_in, const int* in_sizes, int n_in,
                              void* d_out, int out_size, void* d_ws, size_t ws_size,
                              hipStream_t stream) {
    const float* point_feat     = (const float*)d_in[0];
    const float* point_xyz      = (const float*)d_in[1];
    const float* supernode_xyz  = (const float*)d_in[2];
    const int*   neighbor_idx   = (const int*)d_in[3];
    const int*   neighbor_mask  = (const int*)d_in[4];
    const float* supernode_init = (const float*)d_in[5];
    const float* task_emb       = (const float*)d_in[6];
    const float* W1             = (const float*)d_in[7];
    const float* b1             = (const float*)d_in[8];
    const float* W2             = (const float*)d_in[9];
    const float* b2             = (const float*)d_in[10];
    const float* Wf             = (const float*)d_in[11];
    const float* bfv            = (const float*)d_in[12];
    const float* ln_g           = (const float*)d_in[13];
    const float* ln_b           = (const float*)d_in[14];

    char* ws = (char*)d_ws;
    short* w1t  = (short*)ws;                   // 128*168*2 = 43008 B
    short* w2t  = (short*)(ws + 44032);         // 128*136*2 = 34816 B
    float* gb   = (float*)(ws + 78848);         // 8*256*4   =  8192 B
    float* cfl  = (float*)(ws + 87040);         // 16384*4   = 65536 B
    float* out  = (float*)d_out;                // agg scratch between kernels

    prep_kernel<<<40, 256, 0, stream>>>(W1, b1, W2, task_emb, Wf, bfv, w1t, w2t, gb);
    msg_kernel<<<(B_ * M_) / 4, 256, 0, stream>>>(point_feat, point_xyz, supernode_xyz,
                                                  neighbor_idx, neighbor_mask, w1t, out, cfl);
    out_kernel<<<(B_ * M_) / 64, 256, 0, stream>>>(out, w2t, b2, cfl, gb,
                                                   supernode_init, ln_g, ln_b);
}